// Round 9
// baseline (176.730 us; speedup 1.0000x reference)
//
#include <hip/hip_runtime.h>

constexpr int   T   = 4096;
constexpr float VTH = 1.27f;
constexpr int   K   = 16;         // time chunks per row: halves warm-up read volume vs K=32
constexpr int   L   = T / K;      // 256 steps per chunk
constexpr int   LG  = L / 4;      // 64 float4 groups per chunk
constexpr int   WGG = 160;        // warm-up groups = 640 steps (lock fail ~0.068%/boundary)

// ---- h-mask LIF machine (bitwise-validated vs reference: absmax 0.0) ----
// h bit j == spike at (t-1-j). gate (carried) == spike in [t-5, t-1].
__device__ __forceinline__ bool sstep(float x, float decay, float& v, unsigned& h, bool& gate) {
    float t1 = __fmul_rn(decay, v);
    float vd = __fsub_rn(v, t1);           // unfused — matches reference rounding
    float xe = gate ? 0.0f : x;
    float vn = __fadd_rn(vd, xe);
    bool  s  = vn > VTH;
    v = s ? 0.0f : vn;
    bool g4 = (h & 15u) != 0u;
    h = (h << 1) | (s ? 1u : 0u);
    gate = s || g4;
    return s;
}

// vo, so for step t; dvo = dv[t-1] (zero iff spike in [t-6, t]).
__device__ __forceinline__ bool ostep(float x, float decay, float& v, unsigned& h, bool& gate,
                                      float& vo, float& so, float& dvo, float xprev) {
    float t1 = __fmul_rn(decay, v);
    float vd = __fsub_rn(v, t1);
    float xe = gate ? 0.0f : x;
    float vn = __fadd_rn(vd, xe);
    bool  s  = vn > VTH;
    vo = s ? VTH  : vn;
    so = s ? 1.0f : 0.0f;
    v  = s ? 0.0f : vn;
    bool z6 = s || ((h & 63u) != 0u);
    dvo = z6 ? 0.0f : xprev;
    bool g4 = (h & 15u) != 0u;
    h = (h << 1) | (s ? 1u : 0u);
    gate = s || g4;
    return s;
}

__device__ __forceinline__ void ogroup(float4 X, float decay, float& v, unsigned& h, bool& gate,
                                       float& xprev, float4& vo, float4& so,
                                       float& close, float& px, float& py, float& pz) {
    ostep(X.x, decay, v, h, gate, vo.x, so.x, close, xprev); xprev = X.x;
    ostep(X.y, decay, v, h, gate, vo.y, so.y, px,    xprev); xprev = X.y;
    ostep(X.z, decay, v, h, gate, vo.z, so.z, py,    xprev); xprev = X.z;
    ostep(X.w, decay, v, h, gate, vo.w, so.w, pz,    xprev); xprev = X.w;
}

// explicit waits (NO __syncthreads: its vmcnt(0) would drain the DMA pipeline).
// sched_barrier(0) after each asm wait per rule #18.
#define WVM(N) do { asm volatile("s_waitcnt vmcnt(" #N ")" ::: "memory"); \
                    __builtin_amdgcn_sched_barrier(0); } while (0)
#define WLG()  do { asm volatile("s_waitcnt lgkmcnt(0)" ::: "memory"); \
                    __builtin_amdgcn_sched_barrier(0); } while (0)

using GU32 = const __attribute__((address_space(1))) unsigned int;
using LU32 = __attribute__((address_space(3))) unsigned int;

// DMA one 64-row x 8-group tile global->LDS. Instr j: 8 rows x 128 B contiguous; LDS dest
// j*1024 + lane*16 == linear [64][8] float4 (row r = j*8+(lane>>3), phys col lane&7).
// Caller pre-swizzles the per-lane SOURCE column (rule #21): phys col p of row r holds
// logical group p^(r&7) -> reader's b128 access is conflict-free.
__device__ __forceinline__ void stage8(const float* src0, float4* lbuf) {
    LU32* lp = (LU32*)lbuf;
#pragma unroll
    for (int j = 0; j < 8; ++j)
        __builtin_amdgcn_global_load_lds((GU32*)(src0 + (size_t)j * 8 * T),
                                         lp + j * 256, 16, 0, 0);
}

// ---------------- fused speculative chunk kernel ----------------
// 512 single-wave blocks, 24 KB LDS. Outputs held in registers per 32-step pair;
// two shared 8 KB transpose buffers (v+s together, then dv) flushed as
// full-128B-per-row coalesced stores.
__global__ __launch_bounds__(64, 1)
void lif_spec(const float* __restrict__ ode, const float* __restrict__ decay_p,
              float* __restrict__ vout, float* __restrict__ sout, float* __restrict__ dvout,
              float2* __restrict__ Sst, float2* __restrict__ Est, int B) {
    __shared__ float4 xin[64 * 8];         // input tile (single buffer, consume-then-restage)
    __shared__ float4 stgA[64 * 8];        // output transpose buffer (v, then dv)
    __shared__ float4 stgB[64 * 8];        // output transpose buffer (s)

    const int tid = threadIdx.x;
    const int gg  = blockIdx.x * 64;
    const int rb  = gg % B;                // row block base; wave = 64 consecutive rows
    const int k   = gg / B;                // wave-uniform chunk id
    const int b   = rb + tid;
    const float decay = decay_p[0];
    const int t7 = tid & 7, t3 = tid >> 3;
    const int sw = t7 ^ t3;                // swizzled column (source & transposed-read)

    const int g0f = k * LG;                                    // chunk start (groups)
    const int wgg = (k == 0) ? 0 : (g0f < WGG ? g0f : WGG);    // warm-up groups
    const int nw  = wgg >> 3;                                  // warm-up tiles
    const int gstart = g0f - wgg;                              // stream start (groups)

    float v = 0.0f; unsigned h = 0u; bool gate = false;
    float xprev = 0.0f;

    float xla = (k < K - 1) ? ode[(size_t)b * T + (size_t)(k + 1) * L] : 0.0f;

#define STAGE(t) stage8(ode + ((size_t)(rb + t3) * T \
                               + (size_t)(gstart + 8 * (t)) * 4 + sw * 4), xin)
    float4 G0, G1, G2, G3, G4, G5, G6, G7;
#define RD8() do { G0 = xin[tid*8 + (0^t7)]; G1 = xin[tid*8 + (1^t7)]; \
                   G2 = xin[tid*8 + (2^t7)]; G3 = xin[tid*8 + (3^t7)]; \
                   G4 = xin[tid*8 + (4^t7)]; G5 = xin[tid*8 + (5^t7)]; \
                   G6 = xin[tid*8 + (6^t7)]; G7 = xin[tid*8 + (7^t7)]; } while (0)
#define WG4(G) { sstep(G.x, decay, v, h, gate); sstep(G.y, decay, v, h, gate); \
                 sstep(G.z, decay, v, h, gate); sstep(G.w, decay, v, h, gate); }

    STAGE(0);                              // tile 0 in flight

    // ---- warm-up (state only). Chunks 1..2 cover the full prefix -> exact.
    if (nw > 0) {
        const bool t0row = (gstart == 0);
        for (int t = 0; t < nw; ++t) {
            WVM(0);                        // tile t resident (only loads outstanding)
            RD8();
            WLG();                         // tile in regs -> safe to overwrite buffer
            STAGE(t + 1);                  // last warm-up iter stages main tile nw
            if (t == 0 && t0row) {         // t=0 spike does NOT arm the window
                sstep(G0.x, decay, v, h, gate); h = 0u; gate = false;
                sstep(G0.y, decay, v, h, gate);
                sstep(G0.z, decay, v, h, gate);
                sstep(G0.w, decay, v, h, gate);
            } else { WG4(G0) }
            WG4(G1) WG4(G2) WG4(G3) WG4(G4) WG4(G5) WG4(G6) WG4(G7)
        }
    }

    // ---- main: 8 pairs x 8 groups, outputs in regs, staged flushes ----
    float4 VA0, VA1, VA2, VA3, VA4, VA5, VA6, VA7;
    float4 SA0, SA1, SA2, SA3, SA4, SA5, SA6, SA7;
    float4 DA0, DA1, DA2, DA3, DA4, DA5, DA6, DA7;
    float4 DB0, DB1, DB2, DB3, DB4, DB5, DB6, DB7;
    float dumm;

// group: compute into reg targets. CloseL = previous D-group's .w lvalue.
#define OGR(X, Vd, Sd, CloseL, Dd) { \
        ostep(X.x, decay, v, h, gate, Vd.x, Sd.x, CloseL, xprev); xprev = X.x; \
        ostep(X.y, decay, v, h, gate, Vd.y, Sd.y, Dd.x,   xprev); xprev = X.y; \
        ostep(X.z, decay, v, h, gate, Vd.z, Sd.z, Dd.y,   xprev); xprev = X.z; \
        ostep(X.w, decay, v, h, gate, Vd.w, Sd.w, Dd.z,   xprev); xprev = X.w; }

// flush v (stgA) + s (stgB) for pair poff: one write-batch, one wait, one read+store batch
#define FLVS(poff) { \
        stgA[tid*8 + (0^t7)] = VA0; stgA[tid*8 + (1^t7)] = VA1; \
        stgA[tid*8 + (2^t7)] = VA2; stgA[tid*8 + (3^t7)] = VA3; \
        stgA[tid*8 + (4^t7)] = VA4; stgA[tid*8 + (5^t7)] = VA5; \
        stgA[tid*8 + (6^t7)] = VA6; stgA[tid*8 + (7^t7)] = VA7; \
        stgB[tid*8 + (0^t7)] = SA0; stgB[tid*8 + (1^t7)] = SA1; \
        stgB[tid*8 + (2^t7)] = SA2; stgB[tid*8 + (3^t7)] = SA3; \
        stgB[tid*8 + (4^t7)] = SA4; stgB[tid*8 + (5^t7)] = SA5; \
        stgB[tid*8 + (6^t7)] = SA6; stgB[tid*8 + (7^t7)] = SA7; \
        WLG(); \
        _Pragma("unroll") \
        for (int jj = 0; jj < 8; ++jj) { \
            int rr = jj * 8 + t3; \
            size_t off = (size_t)(rb + rr) * T + (size_t)k * L + (poff) * 32 + t7 * 4; \
            *(float4*)(vout + off) = stgA[rr * 8 + sw]; \
            *(float4*)(sout + off) = stgB[rr * 8 + sw]; \
        } \
        WLG(); }

// flush dv of pair poff from reg set D?0..7 through stgA
#define FLDV(R0,R1,R2,R3,R4,R5,R6,R7, poff) { \
        stgA[tid*8 + (0^t7)] = R0; stgA[tid*8 + (1^t7)] = R1; \
        stgA[tid*8 + (2^t7)] = R2; stgA[tid*8 + (3^t7)] = R3; \
        stgA[tid*8 + (4^t7)] = R4; stgA[tid*8 + (5^t7)] = R5; \
        stgA[tid*8 + (6^t7)] = R6; stgA[tid*8 + (7^t7)] = R7; \
        WLG(); \
        _Pragma("unroll") \
        for (int jj = 0; jj < 8; ++jj) { \
            int rr = jj * 8 + t3; \
            size_t off = (size_t)(rb + rr) * T + (size_t)k * L + (poff) * 32 + t7 * 4; \
            *(float4*)(dvout + off) = stgA[rr * 8 + sw]; \
        } \
        WLG(); }

    {   // pair 0 (tile nw) — dv set DA
        WVM(0);
        RD8();
        WLG();
        if (nw > 0) Sst[k * B + b] = make_float2(v, __uint_as_float(h & 127u));
        STAGE(nw + 1);
        if (k == 0) {
            bool s0 = ostep(G0.x, decay, v, h, gate, VA0.x, SA0.x, dumm, xprev); xprev = G0.x;
            h = 0u; gate = false;          // t=0 spike doesn't arm the window
            bool s1 = ostep(G0.y, decay, v, h, gate, VA0.y, SA0.y, DA0.x, xprev); xprev = G0.y;
            ostep(G0.z, decay, v, h, gate, VA0.z, SA0.z, DA0.y, xprev); xprev = G0.z;
            ostep(G0.w, decay, v, h, gate, VA0.w, SA0.w, DA0.z, xprev); xprev = G0.w;
            if (s0 && s1) VA0.z = VTH;     // counter==2 corner: spikes at t=0 and t=1
        } else {
            // first close = dv[t0-1]: owned by chunk k-1's lookahead -> discard
            OGR(G0, VA0, SA0, dumm, DA0)
        }
        OGR(G1, VA1, SA1, DA0.w, DA1) OGR(G2, VA2, SA2, DA1.w, DA2)
        OGR(G3, VA3, SA3, DA2.w, DA3) OGR(G4, VA4, SA4, DA3.w, DA4)
        OGR(G5, VA5, SA5, DA4.w, DA5) OGR(G6, VA6, SA6, DA5.w, DA6)
        OGR(G7, VA7, SA7, DA6.w, DA7)  // DA7.w closes at pair 1's first step
        FLVS(0)
    }

// pair p (1..7), tile nw+p. DP = previous dv set (flushed here), DC = current dv set.
// NOTE: (DP##7).w not DP##7.w — '7.w' is one pp-number token, the paste would be invalid.
// vmcnt ledger: pair 1 entry queue newer-than-tile = FLVS(16) -> WVM(16)
//              (Sst store is OLDER than STAGE(nw+1), drains first);
// pairs 2..7: newer-than-tile = FLDV(8) + FLVS(16) = 24 -> WVM(24).
// Pair 7 issues no restage (STAGE(nw+8) would cross the row end on the last chunk).
#define MPAIR(p, DP, DC, VMN) { \
        WVM(VMN); \
        RD8(); \
        WLG(); \
        if ((p) < 7) STAGE(nw + (p) + 1); \
        OGR(G0, VA0, SA0, (DP##7).w, DC##0) \
        FLDV(DP##0, DP##1, DP##2, DP##3, DP##4, DP##5, DP##6, DP##7, (p) - 1) \
        OGR(G1, VA1, SA1, (DC##0).w, DC##1) OGR(G2, VA2, SA2, (DC##1).w, DC##2) \
        OGR(G3, VA3, SA3, (DC##2).w, DC##3) OGR(G4, VA4, SA4, (DC##3).w, DC##4) \
        OGR(G5, VA5, SA5, (DC##4).w, DC##5) OGR(G6, VA6, SA6, (DC##5).w, DC##6) \
        OGR(G7, VA7, SA7, (DC##6).w, DC##7) \
        FLVS(p) }

    MPAIR(1, DA, DB, 16)
    MPAIR(2, DB, DA, 24)
    MPAIR(3, DA, DB, 24)
    MPAIR(4, DB, DA, 24)
    MPAIR(5, DA, DB, 24)
    MPAIR(6, DB, DA, 24)
    MPAIR(7, DA, DB, 24)
#undef MPAIR

    Est[k * B + b] = make_float2(v, __uint_as_float(h & 127u));   // exit, pre-lookahead

    if (k < K - 1) {                       // lookahead closes dv[t0+L-1]
        float vo_, so_;
        ostep(xla, decay, v, h, gate, vo_, so_, DB7.w, xprev);
    } else {
        DB7.w = ((h & 63u) != 0u) ? 0.0f : xprev;   // dv[T-1]
    }
    FLDV(DB0, DB1, DB2, DB3, DB4, DB5, DB6, DB7, 7)
#undef OGR
#undef FLVS
#undef FLDV
#undef RD8
#undef WG4
#undef STAGE
}

// ---------------- verify + rare chunk-granular repair (exact by induction) ----------------
__global__ __launch_bounds__(64, 1)
void lif_fix(const float* __restrict__ ode, const float* __restrict__ decay_p,
             float* __restrict__ vout, float* __restrict__ sout, float* __restrict__ dvout,
             const float2* __restrict__ Sst, const float2* __restrict__ Est, int B) {
    const int b = blockIdx.x * 64 + threadIdx.x;
    const float decay = decay_p[0];

    float2 E  = Est[b];                    // chunk 0 exit — exact
    float2 S1 = Sst[B + b];
    float2 E1 = Est[B + b];
    for (int k = 1; k < K; ++k) {
        float2 S = S1, Ek = E1;
        if (k + 1 < K) { S1 = Sst[(k + 1) * B + b]; E1 = Est[(k + 1) * B + b]; }
        bool match = (S.x == E.x) && (__float_as_uint(S.y) == __float_as_uint(E.y));
        if (match) { E = Ek; continue; }

        // rerun chunk k from exact entry E, rewriting its outputs (4-group-deep load pipeline)
        const size_t bt = (size_t)b * T;
        const float4* __restrict__ x4 = (const float4*)(ode + bt);
        float4* __restrict__ v4 = (float4*)(vout + bt);
        float4* __restrict__ s4 = (float4*)(sout + bt);
        float4* __restrict__ d4 = (float4*)(dvout + bt);
        const int g0f = k * LG;

        float v = E.x; unsigned h = __float_as_uint(E.y);
        bool gate = (h & 31u) != 0u;
        float xprev = 0.0f;
        float4 pend;

        float4 Q0 = x4[g0f], Q1 = x4[g0f + 1], Q2 = x4[g0f + 2], Q3 = x4[g0f + 3];
        {   // group 0: close (dv[t0-1]) owned by chunk k-1's (exact) lookahead
            float4 vo, so; float cl;
            ogroup(Q0, decay, v, h, gate, xprev, vo, so, cl, pend.x, pend.y, pend.z);
            v4[g0f] = vo; s4[g0f] = so;
            Q0 = x4[g0f + 4];
        }
#define FPROC(cc, Q) { float4 vo, so; float px, py, pz; \
            ogroup(Q, decay, v, h, gate, xprev, vo, so, pend.w, px, py, pz); \
            d4[g0f + (cc) - 1] = pend; \
            pend.x = px; pend.y = py; pend.z = pz; \
            v4[g0f + (cc)] = vo; s4[g0f + (cc)] = so; }
        FPROC(1, Q1) Q1 = x4[g0f + 5];
        FPROC(2, Q2) Q2 = x4[g0f + 6];
        FPROC(3, Q3) Q3 = x4[g0f + 7];
        for (int c0 = 4; c0 < LG; c0 += 4) {
            FPROC(c0,     Q0) Q0 = x4[g0f + (c0 + 4 < LG ? c0 + 4 : LG - 1)];
            FPROC(c0 + 1, Q1) Q1 = x4[g0f + (c0 + 5 < LG ? c0 + 5 : LG - 1)];
            FPROC(c0 + 2, Q2) Q2 = x4[g0f + (c0 + 6 < LG ? c0 + 6 : LG - 1)];
            FPROC(c0 + 3, Q3) Q3 = x4[g0f + (c0 + 7 < LG ? c0 + 7 : LG - 1)];
        }
#undef FPROC
        E = make_float2(v, __uint_as_float(h & 127u));   // corrected exit
        if (k < K - 1) {
            float xla = ode[bt + (size_t)(k + 1) * L];
            float vo_, so_;
            ostep(xla, decay, v, h, gate, vo_, so_, pend.w, xprev);
        } else {
            pend.w = ((h & 63u) != 0u) ? 0.0f : xprev;
        }
        d4[g0f + LG - 1] = pend;
    }
}

extern "C" void kernel_launch(void* const* d_in, const int* in_sizes, int n_in,
                              void* d_out, int out_size, void* d_ws, size_t ws_size,
                              hipStream_t stream) {
    const float* ode   = (const float*)d_in[0];
    const float* decay = (const float*)d_in[1];
    float* out = (float*)d_out;

    const int BT = in_sizes[0];            // B*T
    const int B  = BT / T;                 // 2048

    float* vout  = out;
    float* sout  = out + (size_t)BT;
    float* dvout = out + 2 * (size_t)BT;

    float2* Sst = (float2*)d_ws;           // [K][B]
    float2* Est = Sst + (size_t)K * B;     // [K][B]  (512 KB total)

    lif_spec<<<dim3((B * K) / 64), dim3(64), 0, stream>>>(ode, decay, vout, sout, dvout,
                                                          Sst, Est, B);
    lif_fix<<<dim3(B / 64), dim3(64), 0, stream>>>(ode, decay, vout, sout, dvout,
                                                   Sst, Est, B);
}

// Round 10
// 170.197 us; speedup vs baseline: 1.0384x; 1.0384x over previous
//
#include <hip/hip_runtime.h>

constexpr int   T   = 4096;
constexpr float VTH = 1.27f;
constexpr int   K   = 32;         // time chunks per row (R5/R9 bracketing: K=32 optimal)
constexpr int   L   = T / K;      // 128 steps per chunk
constexpr int   LG  = L / 4;      // 32 float4 groups per chunk
constexpr int   WGG = 160;        // warm-up groups = 640 steps (lock fail ~0.068%/boundary)

// ---- h-mask LIF machine (bitwise-validated vs reference: absmax 0.0) ----
// h bit j == spike at (t-1-j). gate (carried) == spike in [t-5, t-1].
__device__ __forceinline__ bool sstep(float x, float decay, float& v, unsigned& h, bool& gate) {
    float t1 = __fmul_rn(decay, v);
    float vd = __fsub_rn(v, t1);           // unfused — matches reference rounding
    float xe = gate ? 0.0f : x;
    float vn = __fadd_rn(vd, xe);
    bool  s  = vn > VTH;
    v = s ? 0.0f : vn;
    bool g4 = (h & 15u) != 0u;
    h = (h << 1) | (s ? 1u : 0u);
    gate = s || g4;
    return s;
}

// vo, so for step t; dvo = dv[t-1] (zero iff spike in [t-6, t]).
__device__ __forceinline__ bool ostep(float x, float decay, float& v, unsigned& h, bool& gate,
                                      float& vo, float& so, float& dvo, float xprev) {
    float t1 = __fmul_rn(decay, v);
    float vd = __fsub_rn(v, t1);
    float xe = gate ? 0.0f : x;
    float vn = __fadd_rn(vd, xe);
    bool  s  = vn > VTH;
    vo = s ? VTH  : vn;
    so = s ? 1.0f : 0.0f;
    v  = s ? 0.0f : vn;
    bool z6 = s || ((h & 63u) != 0u);
    dvo = z6 ? 0.0f : xprev;
    bool g4 = (h & 15u) != 0u;
    h = (h << 1) | (s ? 1u : 0u);
    gate = s || g4;
    return s;
}

__device__ __forceinline__ void ogroup(float4 X, float decay, float& v, unsigned& h, bool& gate,
                                       float& xprev, float4& vo, float4& so,
                                       float& close, float& px, float& py, float& pz) {
    ostep(X.x, decay, v, h, gate, vo.x, so.x, close, xprev); xprev = X.x;
    ostep(X.y, decay, v, h, gate, vo.y, so.y, px,    xprev); xprev = X.y;
    ostep(X.z, decay, v, h, gate, vo.z, so.z, py,    xprev); xprev = X.z;
    ostep(X.w, decay, v, h, gate, vo.w, so.w, pz,    xprev); xprev = X.w;
}

// explicit waits (NO __syncthreads: its vmcnt(0) would drain the DMA pipeline).
// sched_barrier(0) after each asm wait per rule #18.
#define WVM(N) do { asm volatile("s_waitcnt vmcnt(" #N ")" ::: "memory"); \
                    __builtin_amdgcn_sched_barrier(0); } while (0)
#define WLG()  do { asm volatile("s_waitcnt lgkmcnt(0)" ::: "memory"); \
                    __builtin_amdgcn_sched_barrier(0); } while (0)

using GU32 = const __attribute__((address_space(1))) unsigned int;
using LU32 = __attribute__((address_space(3))) unsigned int;

// DMA one 64-row x 8-group tile global->LDS (into the given ring slot). Instr j: 8 rows
// x 128 B contiguous; LDS dest j*1024 + lane*16 == linear [64][8] float4. Caller
// pre-swizzles the per-lane SOURCE column (rule #21) -> reader's b128 is conflict-free.
__device__ __forceinline__ void stage8(const float* src0, float4* lbuf) {
    LU32* lp = (LU32*)lbuf;
#pragma unroll
    for (int j = 0; j < 8; ++j)
        __builtin_amdgcn_global_load_lds((GU32*)(src0 + (size_t)j * 8 * T),
                                         lp + j * 256, 16, 0, 0);
}

// ---------------- fused speculative chunk kernel ----------------
// 1024 single-wave blocks. LDS 40 KB (= exactly 4 blocks/CU): 3-slot input ring (24 KB,
// prefetch distance 2 tiles ~= 2 pairs of compute in flight) + two 8 KB output transpose
// buffers. Outputs held in registers per 32-step pair, flushed as full-128B-per-row stores.
__global__ __launch_bounds__(64, 1)
void lif_spec(const float* __restrict__ ode, const float* __restrict__ decay_p,
              float* __restrict__ vout, float* __restrict__ sout, float* __restrict__ dvout,
              float2* __restrict__ Sst, float2* __restrict__ Est, int B) {
    __shared__ float4 xin[3 * 512];        // input tile ring (3 slots x 8 KB)
    __shared__ float4 stgA[64 * 8];        // output transpose buffer (v, then dv)
    __shared__ float4 stgB[64 * 8];        // output transpose buffer (s)

    const int tid = threadIdx.x;
    const int gg  = blockIdx.x * 64;
    const int rb  = gg % B;                // row block base; wave = 64 consecutive rows
    const int k   = gg / B;                // wave-uniform chunk id
    const int b   = rb + tid;
    const float decay = decay_p[0];
    const int t7 = tid & 7, t3 = tid >> 3;
    const int sw = t7 ^ t3;                // swizzled column (source & transposed-read)

    const int g0f = k * LG;                                    // chunk start (groups)
    const int wgg = (k == 0) ? 0 : (g0f < WGG ? g0f : WGG);    // warm-up groups
    const int nw  = wgg >> 3;                                  // warm-up tiles
    const int gstart = g0f - wgg;                              // stream start (groups)

    float v = 0.0f; unsigned h = 0u; bool gate = false;
    float xprev = 0.0f;

    float xla = (k < K - 1) ? ode[(size_t)b * T + (size_t)(k + 1) * L] : 0.0f;

#define STAGE(t, sbase) stage8(ode + ((size_t)(rb + t3) * T \
                               + (size_t)(gstart + 8 * (t)) * 4 + sw * 4), (sbase))
    float4 G0, G1, G2, G3, G4, G5, G6, G7;
#define RD8(P) do { G0 = (P)[tid*8 + (0^t7)]; G1 = (P)[tid*8 + (1^t7)]; \
                    G2 = (P)[tid*8 + (2^t7)]; G3 = (P)[tid*8 + (3^t7)]; \
                    G4 = (P)[tid*8 + (4^t7)]; G5 = (P)[tid*8 + (5^t7)]; \
                    G6 = (P)[tid*8 + (6^t7)]; G7 = (P)[tid*8 + (7^t7)]; } while (0)
#define WG4(G) { sstep(G.x, decay, v, h, gate); sstep(G.y, decay, v, h, gate); \
                 sstep(G.z, decay, v, h, gate); sstep(G.w, decay, v, h, gate); }

    STAGE(0, xin);                         // slot 0, tile 0
    STAGE(1, xin + 512);                   // slot 1, tile 1 (distance-2 pipeline primed)
    int sl = 0;                            // ring slot being consumed

    // ---- warm-up (state only). Distance-2 ring: no exposed load latency.
    if (nw > 0) {
        const bool t0row = (gstart == 0);
        for (int t = 0; t < nw; ++t) {
            WVM(8);                        // allow tile t+1 (8 loads); tile t resident
            RD8(xin + sl * 512);
            {   // stage tile t+2 into slot sl+2 (mod 3): never the slot just read
                int st = sl + 2; if (st >= 3) st -= 3;
                STAGE(t + 2, xin + st * 512);   // t+2 <= nw+1: in-row
            }
            sl = (sl == 2) ? 0 : sl + 1;
            if (t == 0 && t0row) {         // t=0 spike does NOT arm the window
                sstep(G0.x, decay, v, h, gate); h = 0u; gate = false;
                sstep(G0.y, decay, v, h, gate);
                sstep(G0.z, decay, v, h, gate);
                sstep(G0.w, decay, v, h, gate);
            } else { WG4(G0) }
            WG4(G1) WG4(G2) WG4(G3) WG4(G4) WG4(G5) WG4(G6) WG4(G7)
        }
    }

    // ---- main: 4 pairs x 8 groups, outputs in regs, staged flushes ----
    float4 VA0, VA1, VA2, VA3, VA4, VA5, VA6, VA7;
    float4 SA0, SA1, SA2, SA3, SA4, SA5, SA6, SA7;
    float4 DA0, DA1, DA2, DA3, DA4, DA5, DA6, DA7;
    float4 DB0, DB1, DB2, DB3, DB4, DB5, DB6, DB7;
    float dumm;

// group: compute into reg targets. CloseL = previous D-group's .w lvalue.
#define OGR(X, Vd, Sd, CloseL, Dd) { \
        ostep(X.x, decay, v, h, gate, Vd.x, Sd.x, CloseL, xprev); xprev = X.x; \
        ostep(X.y, decay, v, h, gate, Vd.y, Sd.y, Dd.x,   xprev); xprev = X.y; \
        ostep(X.z, decay, v, h, gate, Vd.z, Sd.z, Dd.y,   xprev); xprev = X.z; \
        ostep(X.w, decay, v, h, gate, Vd.w, Sd.w, Dd.z,   xprev); xprev = X.w; }

// flush v (stgA) + s (stgB) for pair poff: one write-batch, one wait, one read+store batch
#define FLVS(poff) { \
        stgA[tid*8 + (0^t7)] = VA0; stgA[tid*8 + (1^t7)] = VA1; \
        stgA[tid*8 + (2^t7)] = VA2; stgA[tid*8 + (3^t7)] = VA3; \
        stgA[tid*8 + (4^t7)] = VA4; stgA[tid*8 + (5^t7)] = VA5; \
        stgA[tid*8 + (6^t7)] = VA6; stgA[tid*8 + (7^t7)] = VA7; \
        stgB[tid*8 + (0^t7)] = SA0; stgB[tid*8 + (1^t7)] = SA1; \
        stgB[tid*8 + (2^t7)] = SA2; stgB[tid*8 + (3^t7)] = SA3; \
        stgB[tid*8 + (4^t7)] = SA4; stgB[tid*8 + (5^t7)] = SA5; \
        stgB[tid*8 + (6^t7)] = SA6; stgB[tid*8 + (7^t7)] = SA7; \
        WLG(); \
        _Pragma("unroll") \
        for (int jj = 0; jj < 8; ++jj) { \
            int rr = jj * 8 + t3; \
            size_t off = (size_t)(rb + rr) * T + (size_t)k * L + (poff) * 32 + t7 * 4; \
            *(float4*)(vout + off) = stgA[rr * 8 + sw]; \
            *(float4*)(sout + off) = stgB[rr * 8 + sw]; \
        } \
        WLG(); }

// flush dv of pair poff from reg set D?0..7 through stgA
#define FLDV(R0,R1,R2,R3,R4,R5,R6,R7, poff) { \
        stgA[tid*8 + (0^t7)] = R0; stgA[tid*8 + (1^t7)] = R1; \
        stgA[tid*8 + (2^t7)] = R2; stgA[tid*8 + (3^t7)] = R3; \
        stgA[tid*8 + (4^t7)] = R4; stgA[tid*8 + (5^t7)] = R5; \
        stgA[tid*8 + (6^t7)] = R6; stgA[tid*8 + (7^t7)] = R7; \
        WLG(); \
        _Pragma("unroll") \
        for (int jj = 0; jj < 8; ++jj) { \
            int rr = jj * 8 + t3; \
            size_t off = (size_t)(rb + rr) * T + (size_t)k * L + (poff) * 32 + t7 * 4; \
            *(float4*)(dvout + off) = stgA[rr * 8 + sw]; \
        } \
        WLG(); }

    {   // pair 0 (tile nw) — dv set DA. Queue: tile nw (maybe) + tile nw+1 -> WVM(8).
        WVM(8);
        RD8(xin + sl * 512);
        if (nw > 0) Sst[k * B + b] = make_float2(v, __uint_as_float(h & 127u));
        {   int st = sl + 2; if (st >= 3) st -= 3;
            STAGE(nw + 2, xin + st * 512);     // tile nw+2: in-chunk, always safe
        }
        sl = (sl == 2) ? 0 : sl + 1;
        if (k == 0) {
            bool s0 = ostep(G0.x, decay, v, h, gate, VA0.x, SA0.x, dumm, xprev); xprev = G0.x;
            h = 0u; gate = false;          // t=0 spike doesn't arm the window
            bool s1 = ostep(G0.y, decay, v, h, gate, VA0.y, SA0.y, DA0.x, xprev); xprev = G0.y;
            ostep(G0.z, decay, v, h, gate, VA0.z, SA0.z, DA0.y, xprev); xprev = G0.z;
            ostep(G0.w, decay, v, h, gate, VA0.w, SA0.w, DA0.z, xprev); xprev = G0.w;
            if (s0 && s1) VA0.z = VTH;     // counter==2 corner: spikes at t=0 and t=1
        } else {
            // first close = dv[t0-1]: owned by chunk k-1's lookahead -> discard
            OGR(G0, VA0, SA0, dumm, DA0)
        }
        OGR(G1, VA1, SA1, DA0.w, DA1) OGR(G2, VA2, SA2, DA1.w, DA2)
        OGR(G3, VA3, SA3, DA2.w, DA3) OGR(G4, VA4, SA4, DA3.w, DA4)
        OGR(G5, VA5, SA5, DA4.w, DA5) OGR(G6, VA6, SA6, DA5.w, DA6)
        OGR(G7, VA7, SA7, DA6.w, DA7)  // DA7.w closes at pair 1's first step
        FLVS(0)
    }

// pair p (1..3), tile nw+p (staged 2 pairs earlier). DP = previous dv set, DC = current.
// NOTE: (DP##7).w not DP##7.w — '7.w' is one pp-number token (R8 lesson).
// vmcnt ledger (ops issued after the consumed tile; waits may only be stricter):
//   pair 1: Sst(<=1)+STAGE(nw+2)(8)+FLVS(16) = 24..25 -> WVM(24)
//   pair 2: FLVS_0(16) + STAGE(nw+3)(8)+FLDV_0(8)+FLVS_1(16) = 48 -> WVM(40)
//   pair 3: FLDV_0(8)+FLVS_1(16) + [STAGE?(0/8)]+FLDV_1(8)+FLVS_2(16) = 48..56 -> WVM(40)
// Pairs 2,3 stage tiles nw+4, nw+5 (next chunk's first tiles): suppressed at k==K-1.
#define MPAIR(p, DP, DC, VMN) { \
        WVM(VMN); \
        RD8(xin + sl * 512); \
        if ((p) <= 1 || k < K - 1) { \
            int st = sl + 2; if (st >= 3) st -= 3; \
            STAGE(nw + (p) + 2, xin + st * 512); \
        } \
        sl = (sl == 2) ? 0 : sl + 1; \
        OGR(G0, VA0, SA0, (DP##7).w, DC##0) \
        FLDV(DP##0, DP##1, DP##2, DP##3, DP##4, DP##5, DP##6, DP##7, (p) - 1) \
        OGR(G1, VA1, SA1, (DC##0).w, DC##1) OGR(G2, VA2, SA2, (DC##1).w, DC##2) \
        OGR(G3, VA3, SA3, (DC##2).w, DC##3) OGR(G4, VA4, SA4, (DC##3).w, DC##4) \
        OGR(G5, VA5, SA5, (DC##4).w, DC##5) OGR(G6, VA6, SA6, (DC##5).w, DC##6) \
        OGR(G7, VA7, SA7, (DC##6).w, DC##7) \
        FLVS(p) }

    MPAIR(1, DA, DB, 24)
    MPAIR(2, DB, DA, 40)
    MPAIR(3, DA, DB, 40)
#undef MPAIR

    Est[k * B + b] = make_float2(v, __uint_as_float(h & 127u));   // exit, pre-lookahead

    if (k < K - 1) {                       // lookahead closes dv[t0+L-1]
        float vo_, so_;
        ostep(xla, decay, v, h, gate, vo_, so_, DB7.w, xprev);
    } else {
        DB7.w = ((h & 63u) != 0u) ? 0.0f : xprev;   // dv[T-1]
    }
    FLDV(DB0, DB1, DB2, DB3, DB4, DB5, DB6, DB7, 3)
#undef OGR
#undef FLVS
#undef FLDV
#undef RD8
#undef WG4
#undef STAGE
}

// ---------------- verify + rare chunk-granular repair (exact by induction) ----------------
__global__ __launch_bounds__(64, 1)
void lif_fix(const float* __restrict__ ode, const float* __restrict__ decay_p,
             float* __restrict__ vout, float* __restrict__ sout, float* __restrict__ dvout,
             const float2* __restrict__ Sst, const float2* __restrict__ Est, int B) {
    const int b = blockIdx.x * 64 + threadIdx.x;
    const float decay = decay_p[0];

    float2 E  = Est[b];                    // chunk 0 exit — exact
    float2 S1 = Sst[B + b];
    float2 E1 = Est[B + b];
    for (int k = 1; k < K; ++k) {
        float2 S = S1, Ek = E1;
        if (k + 1 < K) { S1 = Sst[(k + 1) * B + b]; E1 = Est[(k + 1) * B + b]; }
        bool match = (S.x == E.x) && (__float_as_uint(S.y) == __float_as_uint(E.y));
        if (match) { E = Ek; continue; }

        // rerun chunk k from exact entry E, rewriting its outputs (4-group-deep load pipeline)
        const size_t bt = (size_t)b * T;
        const float4* __restrict__ x4 = (const float4*)(ode + bt);
        float4* __restrict__ v4 = (float4*)(vout + bt);
        float4* __restrict__ s4 = (float4*)(sout + bt);
        float4* __restrict__ d4 = (float4*)(dvout + bt);
        const int g0f = k * LG;

        float v = E.x; unsigned h = __float_as_uint(E.y);
        bool gate = (h & 31u) != 0u;
        float xprev = 0.0f;
        float4 pend;

        float4 Q0 = x4[g0f], Q1 = x4[g0f + 1], Q2 = x4[g0f + 2], Q3 = x4[g0f + 3];
        {   // group 0: close (dv[t0-1]) owned by chunk k-1's (exact) lookahead
            float4 vo, so; float cl;
            ogroup(Q0, decay, v, h, gate, xprev, vo, so, cl, pend.x, pend.y, pend.z);
            v4[g0f] = vo; s4[g0f] = so;
            Q0 = x4[g0f + 4];
        }
#define FPROC(cc, Q) { float4 vo, so; float px, py, pz; \
            ogroup(Q, decay, v, h, gate, xprev, vo, so, pend.w, px, py, pz); \
            d4[g0f + (cc) - 1] = pend; \
            pend.x = px; pend.y = py; pend.z = pz; \
            v4[g0f + (cc)] = vo; s4[g0f + (cc)] = so; }
        FPROC(1, Q1) Q1 = x4[g0f + 5];
        FPROC(2, Q2) Q2 = x4[g0f + 6];
        FPROC(3, Q3) Q3 = x4[g0f + 7];
        for (int c0 = 4; c0 < LG; c0 += 4) {
            FPROC(c0,     Q0) Q0 = x4[g0f + (c0 + 4 < LG ? c0 + 4 : LG - 1)];
            FPROC(c0 + 1, Q1) Q1 = x4[g0f + (c0 + 5 < LG ? c0 + 5 : LG - 1)];
            FPROC(c0 + 2, Q2) Q2 = x4[g0f + (c0 + 6 < LG ? c0 + 6 : LG - 1)];
            FPROC(c0 + 3, Q3) Q3 = x4[g0f + (c0 + 7 < LG ? c0 + 7 : LG - 1)];
        }
#undef FPROC
        E = make_float2(v, __uint_as_float(h & 127u));   // corrected exit
        if (k < K - 1) {
            float xla = ode[bt + (size_t)(k + 1) * L];
            float vo_, so_;
            ostep(xla, decay, v, h, gate, vo_, so_, pend.w, xprev);
        } else {
            pend.w = ((h & 63u) != 0u) ? 0.0f : xprev;
        }
        d4[g0f + LG - 1] = pend;
    }
}

extern "C" void kernel_launch(void* const* d_in, const int* in_sizes, int n_in,
                              void* d_out, int out_size, void* d_ws, size_t ws_size,
                              hipStream_t stream) {
    const float* ode   = (const float*)d_in[0];
    const float* decay = (const float*)d_in[1];
    float* out = (float*)d_out;

    const int BT = in_sizes[0];            // B*T
    const int B  = BT / T;                 // 2048

    float* vout  = out;
    float* sout  = out + (size_t)BT;
    float* dvout = out + 2 * (size_t)BT;

    float2* Sst = (float2*)d_ws;           // [K][B]
    float2* Est = Sst + (size_t)K * B;     // [K][B]  (1 MB total)

    lif_spec<<<dim3((B * K) / 64), dim3(64), 0, stream>>>(ode, decay, vout, sout, dvout,
                                                          Sst, Est, B);
    lif_fix<<<dim3(B / 64), dim3(64), 0, stream>>>(ode, decay, vout, sout, dvout,
                                                   Sst, Est, B);
}